// Round 1
// baseline (553.366 us; speedup 1.0000x reference)
//
#include <hip/hip_runtime.h>

#define BB 2048
#define TT 512
#define KK 32

__launch_bounds__(64)
__global__ void crf_kernel(const float* __restrict__ pot_g,
                           const float* __restrict__ trans,
                           const int* __restrict__ seqlen,
                           const int* __restrict__ tagidx,
                           float* __restrict__ out) {
    __shared__ __align__(16) float2 s_ap[KK];       // (alpha, p) staging
    __shared__ unsigned char s_bp[TT * KK];          // backpointers

    const int lane = threadIdx.x;
    const int j = lane & 31;
    const int half = lane >> 5;
    const int i0 = half << 4;
    const int b = blockIdx.x;

    const float* pot = pot_g + (size_t)b * (TT * KK);
    const int* tagrow = tagidx + (size_t)b * TT;
    const int len = seqlen[b];
    const int last = len - 1;

    // transitions column j, source rows i0..i0+15 (exact f32 for viterbi; E=exp for lse matvec)
    float tA[16], tE[16];
#pragma unroll
    for (int k2 = 0; k2 < 16; ++k2) {
        tA[k2] = trans[(i0 + k2) * KK + j];
        tE[k2] = __expf(tA[k2]);
    }

    // t = 0 init
    float pr0 = pot[j];
    float alpha = pr0, beta = pr0;
    int tagchunk = tagrow[lane];                 // tag_idx[b, 0..63]
    int tprev = __shfl(tagchunk, 0, 64);
    float su = 0.0f;
    {
        float ub = __shfl(pr0, tprev, 64);       // pot[b,0,tag0]
        if (lane == 0) su = ub;
    }

    // 2-deep prefetch of potentials rows
    float prCur = pot[min(1, last) * KK + j];
    float prN   = pot[min(2, last) * KK + j];

    for (int t = 1; t <= last; ++t) {
        float prN2 = pot[min(t + 2, last) * KK + j];
        if ((t & 63) == 0) tagchunk = tagrow[t + lane];

        // M = max_i beta_i (butterfly over the 32-group; halves hold identical copies)
        float M = beta;
#pragma unroll
        for (int d = 1; d < 32; d <<= 1)
            M = fmaxf(M, __shfl_xor(M, d, 64));
        float p = __expf(beta - M);              // in (0,1]

        s_ap[j] = make_float2(alpha, p);         // both halves write identical values
        __builtin_amdgcn_wave_barrier();
        __builtin_amdgcn_s_waitcnt(0xC07F);      // lgkmcnt(0): drain ds_write before reads
        __builtin_amdgcn_wave_barrier();

        float m = -3.402823466e38f;
        int bi = i0;
        float ssum = 0.0f;
#pragma unroll
        for (int r = 0; r < 8; ++r) {
            float4 q = *(const float4*)(s_ap + (i0 + 2 * r));  // 2 (alpha,p) pairs
            float s0 = q.x + tA[2 * r];
            bool c0 = s0 > m;                    // strict > : first-max within lane
            bi = c0 ? (i0 + 2 * r) : bi;
            m = c0 ? s0 : m;
            ssum = fmaf(q.y, tE[2 * r], ssum);
            float s1 = q.z + tA[2 * r + 1];
            bool c1 = s1 > m;
            bi = c1 ? (i0 + 2 * r + 1) : bi;
            m = c1 ? s1 : m;
            ssum = fmaf(q.w, tE[2 * r + 1], ssum);
        }
        // combine halves: tie -> lower half (smaller i) = np.argmax first-occurrence
        float mo = __shfl_xor(m, 32, 64);
        int   bo = __shfl_xor(bi, 32, 64);
        float so = __shfl_xor(ssum, 32, 64);
        float mlo = half ? mo : m;
        int   blo = half ? bo : bi;
        float mhi = half ? m : mo;
        int   bhi = half ? bi : bo;
        bool th = mhi > mlo;
        float mm = th ? mhi : mlo;
        int bpj  = th ? bhi : blo;
        float ss = ssum + so;

        s_bp[t * KK + j] = (unsigned char)bpj;

        alpha = prCur + mm;                      // bit-exact vs reference
        beta  = prCur + M + __logf(ss);

        // fused sequence score
        int tcur = __shfl(tagchunk, t & 63, 64);
        float ub = __shfl(prCur, tcur, 64);      // pot[b,t,tag_t]
        float tr = trans[tprev * KK + tcur];     // wave-uniform, L1-resident (4KB)
        su += (lane == 0) ? (ub + tr) : 0.0f;
        tprev = tcur;

        prCur = prN;
        prN = prN2;
    }

    // best_score + last_tag = first-argmax of final alpha
    float bv = alpha;
    int bj = j;
#pragma unroll
    for (int d = 1; d < 32; d <<= 1) {
        float ov = __shfl_xor(bv, d, 64);
        int   oj = __shfl_xor(bj, d, 64);
        bool tk = (ov > bv) || (ov == bv && oj < bj);
        bv = tk ? ov : bv;
        bj = tk ? oj : bj;
    }
    // log_norm = logsumexp(final beta)
    float Mf = beta;
#pragma unroll
    for (int d = 1; d < 32; d <<= 1)
        Mf = fmaxf(Mf, __shfl_xor(Mf, d, 64));
    float e = __expf(beta - Mf);
#pragma unroll
    for (int d = 1; d < 32; d <<= 1)
        e += __shfl_xor(e, d, 64);
    float ln = Mf + __logf(e);

    float* out_tags = out + (size_t)b * TT;
    if (lane == 0) {
        out[(size_t)BB * TT + b] = bv;                 // best_score
        out[(size_t)BB * TT + BB + b] = su - ln;       // log_likelihood
    }
    // t >= len-1: identity backpointers => last_tag everywhere (coalesced fill)
    for (int t = last + lane; t < TT; t += 64)
        out_tags[t] = (float)bj;
    // backtrace (lane 0, LDS pointer chase)
    if (lane == 0) {
        int cur = bj;
        for (int t = last - 1; t >= 0; --t) {
            cur = s_bp[(t + 1) * KK + cur];
            out_tags[t] = (float)cur;
        }
    }
}

extern "C" void kernel_launch(void* const* d_in, const int* in_sizes, int n_in,
                              void* d_out, int out_size, void* d_ws, size_t ws_size,
                              hipStream_t stream) {
    const float* potentials = (const float*)d_in[0];
    const float* transitions = (const float*)d_in[1];
    const int* sequence_lengths = (const int*)d_in[2];
    const int* tag_indices = (const int*)d_in[3];
    float* out = (float*)d_out;
    crf_kernel<<<BB, 64, 0, stream>>>(potentials, transitions, sequence_lengths,
                                      tag_indices, out);
}

// Round 2
// 446.824 us; speedup vs baseline: 1.2384x; 1.2384x over previous
//
#include <hip/hip_runtime.h>

#define BB 2048
#define TT 512
#define KK 32

// 4-source viterbi block: strict > keeps first occurrence (np.argmax semantics)
#define VBLK(q, t0, t1, t2, t3, base, m, bi) do {                       \
    float s0_ = (q).x + (t0), s1_ = (q).y + (t1);                       \
    float s2_ = (q).z + (t2), s3_ = (q).w + (t3);                       \
    m = s0_; bi = (base);                                               \
    if (s1_ > m) { m = s1_; bi = (base) + 1; }                          \
    if (s2_ > m) { m = s2_; bi = (base) + 2; }                          \
    if (s3_ > m) { m = s3_; bi = (base) + 3; }                          \
} while (0)

__launch_bounds__(128)
__global__ void crf_kernel(const float* __restrict__ pot_g,
                           const float* __restrict__ trans,
                           const int* __restrict__ seqlen,
                           const int* __restrict__ tagidx,
                           float* __restrict__ out) {
    __shared__ __align__(16) float s_a[KK];          // alpha broadcast (wave 0)
    __shared__ __align__(16) float s_p[KK];          // p broadcast (wave 1)
    __shared__ unsigned char s_bp[TT * KK];          // backpointers (wave 0)

    const int tid  = threadIdx.x;
    const int wave = tid >> 6;
    const int lane = tid & 63;
    const int j    = lane & 31;
    const int half = lane >> 5;
    const int i0   = half << 4;
    const int b    = blockIdx.x;

    const float* pot = pot_g + (size_t)b * (TT * KK);
    const int len  = seqlen[b];
    const int last = len - 1;
    float* out_tags = out + (size_t)b * TT;

    if (wave == 0) {
        // ================= Viterbi wave =================
        float tA[16];
#pragma unroll
        for (int k = 0; k < 16; ++k) tA[k] = trans[(i0 + k) * KK + j];

        float alpha = pot[j];
        float prCur = pot[min(1, last) * KK + j];
        float prN   = pot[min(2, last) * KK + j];

        for (int t = 1; t <= last; ++t) {
            float prN2 = pot[min(t + 2, last) * KK + j];

            if (half == 0) s_a[j] = alpha;
            __builtin_amdgcn_wave_barrier();
            __builtin_amdgcn_s_waitcnt(0xC07F);   // lgkmcnt(0)
            __builtin_amdgcn_wave_barrier();

            const float4 q0 = *(const float4*)(s_a + i0);
            const float4 q1 = *(const float4*)(s_a + i0 + 4);
            const float4 q2 = *(const float4*)(s_a + i0 + 8);
            const float4 q3 = *(const float4*)(s_a + i0 + 12);

            float m0, m1, m2, m3; int b0, b1, b2, b3;
            VBLK(q0, tA[0],  tA[1],  tA[2],  tA[3],  i0 + 0,  m0, b0);
            VBLK(q1, tA[4],  tA[5],  tA[6],  tA[7],  i0 + 4,  m1, b1);
            VBLK(q2, tA[8],  tA[9],  tA[10], tA[11], i0 + 8,  m2, b2);
            VBLK(q3, tA[12], tA[13], tA[14], tA[15], i0 + 12, m3, b3);
            if (m1 > m0) { m0 = m1; b0 = b1; }     // later block: strict
            if (m3 > m2) { m2 = m3; b2 = b3; }
            if (m2 > m0) { m0 = m2; b0 = b2; }

            // cross-half combine; low half = sources 0-15 (earlier) wins ties
            float om = __shfl_xor(m0, 32, 64);
            int   ob = __shfl_xor(b0, 32, 64);
            bool take = half ? (om >= m0) : (om > m0);
            float mm = take ? om : m0;
            int  bpj = take ? ob : b0;

            if (half == 0) s_bp[t * KK + j] = (unsigned char)bpj;
            alpha = prCur + mm;                    // bit-exact recursion

            prCur = prN; prN = prN2;
        }

        // first-argmax of final alpha (both halves hold identical alpha)
        float bv = alpha; int bj = j;
#pragma unroll
        for (int d = 1; d < 32; d <<= 1) {
            float ov = __shfl_xor(bv, d, 64);
            int   oj = __shfl_xor(bj, d, 64);
            if (ov > bv || (ov == bv && oj < bj)) { bv = ov; bj = oj; }
        }
        if (lane == 0) out[(size_t)BB * TT + b] = bv;   // best_score

        // tail fill: t >= len-1 -> last_tag
        for (int t = last + lane; t < TT; t += 64) out_tags[t] = (float)bj;

        // cooperative backtrace: row-loads + shfl chase, 32 steps/chunk
        __builtin_amdgcn_wave_barrier();
        __builtin_amdgcn_s_waitcnt(0xC07F);
        __builtin_amdgcn_wave_barrier();
        int cur = bj;
        for (int thi = last; thi >= 1; thi -= 32) {
            int tlo = thi - 31; if (tlo < 1) tlo = 1;
            int nn = thi - tlo + 1;
            int rv[32];
#pragma unroll
            for (int r = 0; r < 32; ++r) {
                int t = tlo + r; t = t > thi ? thi : t;
                rv[r] = s_bp[t * KK + (lane & 31)];
            }
            int tagreg = 0;
#pragma unroll
            for (int r = 31; r >= 0; --r) {
                if (r < nn) {                       // wave-uniform
                    cur = __shfl(rv[r], cur, 64);   // cur = bp[t][cur]
                    tagreg = (lane == r) ? cur : tagreg;
                }
            }
            if (lane < nn) out_tags[tlo - 1 + lane] = (float)tagreg;
        }
    } else {
        // ================= LSE + sequence-score wave =================
        float tE[16];
#pragma unroll
        for (int k = 0; k < 16; ++k) tE[k] = __expf(trans[(i0 + k) * KK + j]);

        // sequence score: strided gather prologue
        const int* tagrow = tagidx + (size_t)b * TT;
        float su = 0.0f;
#pragma unroll
        for (int c = 0; c < TT / 64; ++c) {
            int t = c * 64 + lane;
            if (t < len) {
                int tg = tagrow[t];
                su += pot[t * KK + tg];
                if (t < last) {
                    int tg2 = tagrow[t + 1];
                    su += trans[tg * KK + tg2];
                }
            }
        }
#pragma unroll
        for (int d = 1; d < 64; d <<= 1) su += __shfl_xor(su, d, 64);

        float beta = pot[j];
        float M = beta;                              // exact max at t=0
#pragma unroll
        for (int d = 1; d < 32; d <<= 1) M = fmaxf(M, __shfl_xor(M, d, 64));

        float prCur = pot[min(1, last) * KK + j];
        float prN   = pot[min(2, last) * KK + j];

        for (int t = 1; t <= last; ++t) {
            float prN2 = pot[min(t + 2, last) * KK + j];

            float p = __expf(beta - M);              // M stale by <=1 step: safe
            if (half == 0) s_p[j] = p;
            __builtin_amdgcn_wave_barrier();
            __builtin_amdgcn_s_waitcnt(0xC07F);      // lgkmcnt(0)
            __builtin_amdgcn_wave_barrier();

            // next step's stale max: off critical path, overlaps matvec
            float Mn = beta;
#pragma unroll
            for (int d = 1; d < 32; d <<= 1) Mn = fmaxf(Mn, __shfl_xor(Mn, d, 64));

            const float4 q0 = *(const float4*)(s_p + i0);
            const float4 q1 = *(const float4*)(s_p + i0 + 4);
            const float4 q2 = *(const float4*)(s_p + i0 + 8);
            const float4 q3 = *(const float4*)(s_p + i0 + 12);
            float a0 = fmaf(q0.x, tE[0],  q0.y * tE[1]);
            a0 = fmaf(q0.z, tE[2],  a0); a0 = fmaf(q0.w, tE[3],  a0);
            float a1 = fmaf(q1.x, tE[4],  q1.y * tE[5]);
            a1 = fmaf(q1.z, tE[6],  a1); a1 = fmaf(q1.w, tE[7],  a1);
            float a2 = fmaf(q2.x, tE[8],  q2.y * tE[9]);
            a2 = fmaf(q2.z, tE[10], a2); a2 = fmaf(q2.w, tE[11], a2);
            float a3 = fmaf(q3.x, tE[12], q3.y * tE[13]);
            a3 = fmaf(q3.z, tE[14], a3); a3 = fmaf(q3.w, tE[15], a3);
            float ssum = (a0 + a1) + (a2 + a3);
            ssum += __shfl_xor(ssum, 32, 64);        // cross-half partial

            beta = prCur + M + __logf(ssum);
            M = Mn;
            prCur = prN; prN = prN2;
        }

        // final logsumexp (exact)
        float Mf = beta;
#pragma unroll
        for (int d = 1; d < 32; d <<= 1) Mf = fmaxf(Mf, __shfl_xor(Mf, d, 64));
        float e = __expf(beta - Mf);
#pragma unroll
        for (int d = 1; d < 32; d <<= 1) e += __shfl_xor(e, d, 64);
        float ln = Mf + __logf(e);

        if (lane == 0) out[(size_t)BB * TT + BB + b] = su - ln;  // log_likelihood
    }
}

extern "C" void kernel_launch(void* const* d_in, const int* in_sizes, int n_in,
                              void* d_out, int out_size, void* d_ws, size_t ws_size,
                              hipStream_t stream) {
    const float* potentials = (const float*)d_in[0];
    const float* transitions = (const float*)d_in[1];
    const int* sequence_lengths = (const int*)d_in[2];
    const int* tag_indices = (const int*)d_in[3];
    float* out = (float*)d_out;
    crf_kernel<<<BB, 128, 0, stream>>>(potentials, transitions, sequence_lengths,
                                       tag_indices, out);
}